// Round 12
// baseline (329.477 us; speedup 1.0000x reference)
//
#include <hip/hip_runtime.h>

#define NEG_SLOPE 0.01f
#define B_ 8
#define N_ 2048
#define F_ 512

typedef unsigned short u16;
typedef unsigned int u32;
typedef __attribute__((ext_vector_type(8))) unsigned short u16x8;
typedef __attribute__((ext_vector_type(4))) unsigned short u16x4;
typedef __attribute__((ext_vector_type(4))) unsigned int u32x4;
typedef __attribute__((ext_vector_type(8))) _Float16 f16x8;
typedef __attribute__((ext_vector_type(2))) _Float16 f16x2;
typedef __attribute__((ext_vector_type(4))) float f32x4;

__device__ __forceinline__ f32x4 mfma16f(u16x8 a, u16x8 b, f32x4 c) {
    return __builtin_amdgcn_mfma_f32_16x16x32_f16(
        __builtin_bit_cast(f16x8, a), __builtin_bit_cast(f16x8, b), c, 0, 0, 0);
}

__device__ __forceinline__ void load_lds16(const void* g, void* l) {
    __builtin_amdgcn_global_load_lds(
        (__attribute__((address_space(1))) void*)(void*)g,
        (__attribute__((address_space(3))) void*)l, 16, 0, 0);
}

__device__ __forceinline__ u32 fkey(float f) {        // monotone float->uint
    const u32 u = __float_as_uint(f);
    return (u & 0x80000000u) ? ~u : (u | 0x80000000u);
}
__device__ __forceinline__ float fdec(u32 k) {        // inverse
    return (k & 0x80000000u) ? __uint_as_float(k & 0x7FFFFFFFu)
                             : __uint_as_float(~k);
}

// ---- fused prep: Wk -> f16 transposed [N][K]; ws2/wn2/csn; init anmm ----
__global__ __launch_bounds__(256) void prep_all(const float* __restrict__ Wk,
                                                const float* __restrict__ bk,
                                                const float* __restrict__ ws,
                                                const float* __restrict__ bs,
                                                const float* __restrict__ wn,
                                                const float* __restrict__ bn,
                                                u16* __restrict__ Wf,
                                                float* __restrict__ ws2,
                                                float* __restrict__ wn2,
                                                float* __restrict__ csn,
                                                u32* __restrict__ anmm) {
    const int bid = blockIdx.x, t = threadIdx.x;
    if (bid < 1024) {                        // Wk [k][n] -> f16 WfT [n][k]
        const int id = bid * 256 + t;        // coalesced read, scattered 2B write
        const int k = id >> 9, n = id & 511;
        ((_Float16*)Wf)[(size_t)n * 512 + k] = (_Float16)Wk[id];
        return;
    }
    const int lane = t & 63, w = t >> 6;
    if (bid == 1282) {                       // init batch an min/max keys
        if (t < 16) anmm[t] = (t & 1) ? 0xFFFFFFFFu : 0u;
        return;
    }
    if (bid >= 1280) {                       // csn = {bk.ws+bs, bk.wn+bn}
        if (w == 0) {
            const int sel = bid - 1280;
            const float* vec = sel ? wn : ws;
            const float4 b0 = *(const float4*)(bk + lane * 8);
            const float4 b1 = *(const float4*)(bk + lane * 8 + 4);
            const float4 v0 = *(const float4*)(vec + lane * 8);
            const float4 v1 = *(const float4*)(vec + lane * 8 + 4);
            float d = b0.x * v0.x + b0.y * v0.y + b0.z * v0.z + b0.w * v0.w +
                      b1.x * v1.x + b1.y * v1.y + b1.z * v1.z + b1.w * v1.w;
#pragma unroll
            for (int m = 32; m; m >>= 1) d += __shfl_xor(d, m);
            if (lane == 0) csn[sel] = d + (sel ? bn[0] : bs[0]);
        }
        return;
    }
    const int W = (bid - 1024) * 4 + w;      // 0..1023
    const int k = W & 511;
    const float* vec = (W < 512) ? ws : wn;
    const float4 w0 = *(const float4*)(Wk + (size_t)k * 512 + lane * 8);
    const float4 w1 = *(const float4*)(Wk + (size_t)k * 512 + lane * 8 + 4);
    const float4 v0 = *(const float4*)(vec + lane * 8);
    const float4 v1 = *(const float4*)(vec + lane * 8 + 4);
    float d = w0.x * v0.x + w0.y * v0.y + w0.z * v0.z + w0.w * v0.w +
              w1.x * v1.x + w1.y * v1.y + w1.z * v1.z + w1.w * v1.w;
#pragma unroll
    for (int m = 32; m; m >>= 1) d += __shfl_xor(d, m);
    if (lane == 0) ((W < 512) ? ws2 : wn2)[k] = d;
}

// ---- feat^T = (X @ Wk + bk)^T : f16 MFMA, output [b][f=512][j=2048] f16 ----
__global__ __launch_bounds__(256) void gemm_feat(const float* __restrict__ X,
                                                 const u16* __restrict__ Wf,
                                                 const float* __restrict__ bk,
                                                 u16* __restrict__ featT) {
    __shared__ u16 Af[128 * 64];
    __shared__ u16 Bf[128 * 64];
    const int t = threadIdx.x;
    const int lane = t & 63;
    const int w = t >> 6;
    const int bid = blockIdx.x;
    const int tm = (bid & 7) * 16 + (bid >> 5);   // XCD swizzle: batch b on XCD b
    const int tn = (bid >> 3) & 3;
    const int wr = w >> 1, wc = w & 1;

    f32x4 acc[4][4];
#pragma unroll
    for (int m = 0; m < 4; ++m)
#pragma unroll
        for (int n = 0; n < 4; ++n) acc[m][n] = {0.f, 0.f, 0.f, 0.f};

    const int lrow = lane >> 3;
    const int scol = ((lane & 7) ^ lrow) * 8;
    const u16* Bbase = Wf + ((size_t)(tn * 128 + w * 8 + lrow)) * 512 + scol;
    u16* BfW = Bf + (w * 8) * 64;

    const int arow = t >> 3;
    const int akk = (t & 7) * 8;
    const float* Abase = X + ((size_t)(tm * 128 + arow)) * 512 + akk;
    u16* AfW = Af + arow * 64 + (akk ^ ((arow & 7) * 8));

    for (int k0 = 0; k0 < 512; k0 += 64) {
#pragma unroll
        for (int iss = 0; iss < 4; ++iss)
            load_lds16(Bbase + (size_t)(iss * 32) * 512 + k0, BfW + iss * 32 * 64);
#pragma unroll
        for (int p = 0; p < 4; ++p) {
            const float4 x0 = *(const float4*)(Abase + (size_t)(p * 32) * 512 + k0);
            const float4 x1 = *(const float4*)(Abase + (size_t)(p * 32) * 512 + k0 + 4);
            const float xv[8] = {x0.x, x0.y, x0.z, x0.w, x1.x, x1.y, x1.z, x1.w};
            u16x8 hv;
#pragma unroll
            for (int e = 0; e < 8; ++e)
                hv[e] = __builtin_bit_cast(u16, (_Float16)xv[e]);
            *(u16x8*)(AfW + p * 32 * 64) = hv;
        }
        __syncthreads();
        const int swz = (lane & 7) * 8;
#pragma unroll
        for (int kk = 0; kk < 64; kk += 32) {
            u16x8 af[4], bf[4];
            const int aoff = (kk + (lane >> 4) * 8) ^ swz;
#pragma unroll
            for (int m = 0; m < 4; ++m)
                af[m] = *(const u16x8*)(Af + (wr * 64 + m * 16 + (lane & 15)) * 64 + aoff);
#pragma unroll
            for (int n = 0; n < 4; ++n)
                bf[n] = *(const u16x8*)(Bf + (wc * 64 + n * 16 + (lane & 15)) * 64 + aoff);
#pragma unroll
            for (int m = 0; m < 4; ++m)
#pragma unroll
                for (int n = 0; n < 4; ++n)
                    acc[m][n] = mfma16f(af[m], bf[n], acc[m][n]);
        }
        __syncthreads();
    }

    const int crow0 = tm * 128 + wr * 64;
    const int ccol0 = tn * 128 + wc * 64;
#pragma unroll
    for (int n = 0; n < 4; ++n) {
        const int gc = ccol0 + n * 16 + (lane & 15);      // f-col 0..511
        const float bkv = bk[gc];
#pragma unroll
        for (int m = 0; m < 4; ++m) {
            const int gr = crow0 + m * 16 + (lane >> 4) * 4;  // global row
            const int b = gr >> 11, j = gr & 2047;
            u16x4 pk;
#pragma unroll
            for (int r = 0; r < 4; ++r)
                pk[r] = __builtin_bit_cast(u16, (_Float16)(acc[m][n][r] + bkv));
            *(u16x4*)(featT + ((size_t)(b * 512 + gc)) * 2048 + j) = pk;  // 8B, j%4==0
        }
    }
}

// -- a_self/a_neigh from X (fp32-exact) + block-reduced batch an min/max atomics --
__global__ __launch_bounds__(256) void dots_x(const float* __restrict__ X,
                                              const float* __restrict__ ws2,
                                              const float* __restrict__ wn2,
                                              const float* __restrict__ csn,
                                              float* __restrict__ a_self,
                                              float* __restrict__ a_neigh,
                                              u32* __restrict__ anmm) {
    __shared__ float redn[4];
    const int t = threadIdx.x, lane = t & 63, w = t >> 6;
    const int row = blockIdx.x * 4 + w;
    const float4 f0 = *(const float4*)(X + (size_t)row * 512 + lane * 8);
    const float4 f1 = *(const float4*)(X + (size_t)row * 512 + lane * 8 + 4);
    const float fv[8] = {f0.x, f0.y, f0.z, f0.w, f1.x, f1.y, f1.z, f1.w};
    const float4 sa = *(const float4*)(ws2 + lane * 8);
    const float4 sb = *(const float4*)(ws2 + lane * 8 + 4);
    const float4 na = *(const float4*)(wn2 + lane * 8);
    const float4 nb = *(const float4*)(wn2 + lane * 8 + 4);
    float ds = fv[0] * sa.x + fv[1] * sa.y + fv[2] * sa.z + fv[3] * sa.w +
               fv[4] * sb.x + fv[5] * sb.y + fv[6] * sb.z + fv[7] * sb.w;
    float dn = fv[0] * na.x + fv[1] * na.y + fv[2] * na.z + fv[3] * na.w +
               fv[4] * nb.x + fv[5] * nb.y + fv[6] * nb.z + fv[7] * nb.w;
#pragma unroll
    for (int m = 32; m; m >>= 1) {
        ds += __shfl_xor(ds, m);
        dn += __shfl_xor(dn, m);
    }
    const float dnf = dn + csn[1];
    if (lane == 0) {
        a_self[row] = ds + csn[0];
        a_neigh[row] = dnf;
        redn[w] = dnf;
    }
    __syncthreads();
    if (t == 0) {
        const float mx = fmaxf(fmaxf(redn[0], redn[1]), fmaxf(redn[2], redn[3]));
        const float mn = fminf(fminf(redn[0], redn[1]), fminf(redn[2], redn[3]));
        const int b = row >> 11;             // all 4 rows in same batch
        atomicMax(&anmm[b * 2], fkey(mx));
        atomicMin(&anmm[b * 2 + 1], fkey(mn));
    }
}

// ---- dense flash PV: per block 64 rows x 256 feat cols, K=2048 over mask ----
// P computed in-register (rank-1 scores + mask), f16 via cvt_pkrtz; feat^T tile
// staged to LDS (XOR-swizzled chunks); 16x16x32 f16 MFMA; row-sum in f32.
__global__ __launch_bounds__(256) void attn_dense(const float* __restrict__ A,
                                                  const u16* __restrict__ featT,
                                                  const float* __restrict__ a_self,
                                                  const float* __restrict__ a_neigh,
                                                  const u32* __restrict__ anmm,
                                                  float* __restrict__ out) {
    __shared__ float an_lds[N_];
    __shared__ u16 bt[1024 * 8];             // 16 KB: 256 n x 4 chunks x 16B
    const int bid = blockIdx.x;              // 512 = 8 b (XCD) x 32 mt x 2 nt
    const int b = bid & 7;
    const int mt = (bid >> 3) & 31;
    const int nt = bid >> 8;
    const int t = threadIdx.x, lane = t & 63, w = t >> 6;
    const int mq = w >> 1, nh = w & 1;       // wave tile: M=32 (2 frags), N=128 (8)
    const int mR = mt * 64 + mq * 32;
    const int nC = nt * 256 + nh * 128;

    {   // preload a_neigh for batch (8 KB)
        const f32x4* src = (const f32x4*)(a_neigh + (size_t)b * N_);
        ((f32x4*)an_lds)[t] = src[t];
        ((f32x4*)an_lds)[256 + t] = src[256 + t];
    }

    const float asi0 = a_self[(size_t)b * N_ + mR + (lane & 15)];
    const float asi1 = a_self[(size_t)b * N_ + mR + 16 + (lane & 15)];
    const float anmax = fdec(anmm[b * 2]);
    const float anmin = fdec(anmm[b * 2 + 1]);
    float um0 = asi0 > 0.f ? asi0 * anmax : asi0 * anmin;
    um0 = fmaxf(um0, 0.01f * um0);           // lrelu of unmasked max score
    float um1 = asi1 > 0.f ? asi1 * anmax : asi1 * anmin;
    um1 = fmaxf(um1, 0.01f * um1);
    const float uoff0 = um0 - 7.f, uoff1 = um1 - 7.f;   // p = exp(s-umax+7) <= e^7

    const float* A0 = A + ((size_t)b * N_ + mR + (lane & 15)) * N_ + (lane >> 4) * 8;
    const float* A1 = A0 + (size_t)16 * N_;

    // staging constants: slot = i*256 + t; LDS holds chunk (c ^ ((n>>1)&3)) at slot c
    int slotn[4], csrc[4];
#pragma unroll
    for (int i = 0; i < 4; ++i) {
        const int slot = i * 256 + t;
        slotn[i] = slot >> 2;
        csrc[i] = (slot & 3) ^ ((slotn[i] >> 1) & 3);
    }
    const u16* ftb = featT + (size_t)(b * 512 + nt * 256) * 2048;

    f32x4 acc[2][8];
#pragma unroll
    for (int ma = 0; ma < 2; ++ma)
#pragma unroll
        for (int nf = 0; nf < 8; ++nf) acc[ma][nf] = {0.f, 0.f, 0.f, 0.f};
    float ssum0 = 0.f, ssum1 = 0.f;
    const int bbyte = (((lane >> 4) ^ (((lane & 15) >> 1) & 3)) * 16);
    const char* btb = (const char*)bt + (nh * 128 + (lane & 15)) * 64 + bbyte;

    for (int k0 = 0; k0 < N_; k0 += 32) {
#pragma unroll
        for (int i = 0; i < 4; ++i)
            load_lds16(ftb + (size_t)slotn[i] * 2048 + k0 + csrc[i] * 8,
                       (char*)bt + (i * 256 + w * 64) * 16);   // wave-uniform dest
        const f32x4 a0a = __builtin_nontemporal_load((const f32x4*)(A0 + k0));
        const f32x4 a0b = __builtin_nontemporal_load((const f32x4*)(A0 + k0 + 4));
        const f32x4 a1a = __builtin_nontemporal_load((const f32x4*)(A1 + k0));
        const f32x4 a1b = __builtin_nontemporal_load((const f32x4*)(A1 + k0 + 4));
        __syncthreads();                      // drains vmcnt (staging + A loads)

        const f32x4 anA = *(const f32x4*)&an_lds[k0 + (lane >> 4) * 8];
        const f32x4 anB = *(const f32x4*)&an_lds[k0 + (lane >> 4) * 8 + 4];
        const float anv[8] = {anA.x, anA.y, anA.z, anA.w, anB.x, anB.y, anB.z, anB.w};
        const float av0[8] = {a0a.x, a0a.y, a0a.z, a0a.w, a0b.x, a0b.y, a0b.z, a0b.w};
        const float av1[8] = {a1a.x, a1a.y, a1a.z, a1a.w, a1b.x, a1b.y, a1b.z, a1b.w};

        float p0[8], p1[8];
#pragma unroll
        for (int e = 0; e < 8; ++e) {
            float s = asi0 * anv[e];
            s = fmaxf(s, 0.01f * s);          // leaky-relu in 2 ops
            float p = __expf(s - uoff0);
            p = (av0[e] != 0.f) ? p : 0.f;
            ssum0 += p;
            p0[e] = p;
        }
#pragma unroll
        for (int e = 0; e < 8; ++e) {
            float s = asi1 * anv[e];
            s = fmaxf(s, 0.01f * s);
            float p = __expf(s - uoff1);
            p = (av1[e] != 0.f) ? p : 0.f;
            ssum1 += p;
            p1[e] = p;
        }
        u32x4 w0, w1;
#pragma unroll
        for (int e2 = 0; e2 < 4; ++e2) {
            w0[e2] = __builtin_bit_cast(u32,
                __builtin_amdgcn_cvt_pkrtz(p0[2 * e2], p0[2 * e2 + 1]));
            w1[e2] = __builtin_bit_cast(u32,
                __builtin_amdgcn_cvt_pkrtz(p1[2 * e2], p1[2 * e2 + 1]));
        }
        const u16x8 P0 = __builtin_bit_cast(u16x8, w0);
        const u16x8 P1 = __builtin_bit_cast(u16x8, w1);

#pragma unroll
        for (int nf = 0; nf < 8; ++nf) {
            const u16x8 bf = *(const u16x8*)(btb + nf * 1024);
            acc[0][nf] = mfma16f(P0, bf, acc[0][nf]);
            acc[1][nf] = mfma16f(P1, bf, acc[1][nf]);
        }
        __syncthreads();
    }

    // row sums: combine 4 k-groups, then redistribute to C-row layout
    ssum0 += __shfl_xor(ssum0, 16); ssum0 += __shfl_xor(ssum0, 32);
    ssum1 += __shfl_xor(ssum1, 16); ssum1 += __shfl_xor(ssum1, 32);
    float inv0[4], inv1[4];
#pragma unroll
    for (int r = 0; r < 4; ++r) {
        inv0[r] = 1.f / __shfl(ssum0, (lane >> 4) * 4 + r);
        inv1[r] = 1.f / __shfl(ssum1, (lane >> 4) * 4 + r);
    }

#pragma unroll
    for (int ma = 0; ma < 2; ++ma) {
        const int rowg = b * N_ + mR + ma * 16 + (lane >> 4) * 4;
#pragma unroll
        for (int nf = 0; nf < 8; ++nf) {
            const int col = nC + nf * 16 + (lane & 15);
#pragma unroll
            for (int r = 0; r < 4; ++r) {
                const float iv = ma ? inv1[r] : inv0[r];
                const float val = tanhf(acc[ma][nf][r] * iv);
                float* p = out + (size_t)(rowg + r) * (8 * F_) + col;
#pragma unroll
                for (int h = 0; h < 8; ++h)
                    __builtin_nontemporal_store(val, p + h * F_);
            }
        }
    }
}

extern "C" void kernel_launch(void* const* d_in, const int* in_sizes, int n_in,
                              void* d_out, int out_size, void* d_ws, size_t ws_size,
                              hipStream_t stream) {
    const float* X  = (const float*)d_in[0];
    const float* A  = (const float*)d_in[1];
    const float* Wk = (const float*)d_in[2];
    const float* bk = (const float*)d_in[3];
    const float* ws = (const float*)d_in[4];
    const float* bs = (const float*)d_in[5];
    const float* wn = (const float*)d_in[6];
    const float* bn = (const float*)d_in[7];
    float* out = (float*)d_out;

    char* wsb = (char*)d_ws;
    u16*   featT   = (u16*)(wsb);                  // 16 MiB f16 [b][f][j]
    u16*   Wf      = (u16*)(wsb + 16777216);       // 0.5 MiB
    float* a_self  = (float*)(wsb + 17301504);     // 64 KiB
    float* a_neigh = (float*)(wsb + 17367040);     // 64 KiB
    float* ws2     = (float*)(wsb + 17432576);     // 2 KiB
    float* wn2     = (float*)(wsb + 17434624);     // 2 KiB
    float* csn     = (float*)(wsb + 17436672);     // 8 B
    u32*   anmm    = (u32*)(wsb + 17440768);       // 64 B

    prep_all   <<<dim3(1283), dim3(256), 0, stream>>>(Wk, bk, ws, bs, wn, bn, Wf, ws2, wn2, csn, anmm);
    dots_x     <<<dim3(4096), dim3(256), 0, stream>>>(X, ws2, wn2, csn, a_self, a_neigh, anmm);
    gemm_feat  <<<dim3(512),  dim3(256), 0, stream>>>(X, Wf, bk, featT);
    attn_dense <<<dim3(512),  dim3(256), 0, stream>>>(A, featT, a_self, a_neigh, anmm, out);
}